// Round 9
// baseline (134.807 us; speedup 1.0000x reference)
//
#include <hip/hip_runtime.h>
#include <math.h>

// Problem constants
#define B_  8
#define D_  128
#define L_  2048
#define H_  8
#define DH_ 16

#define LOG2E 1.4426950408889634f

typedef __bf16 bf16x8 __attribute__((ext_vector_type(8)));
typedef float  floatx4 __attribute__((ext_vector_type(4)));
typedef float  floatx16 __attribute__((ext_vector_type(16)));

#if __has_builtin(__builtin_amdgcn_exp2f)
#define EXP2(x) __builtin_amdgcn_exp2f(x)
#else
#define EXP2(x) exp2f(x)
#endif

// ---------------------------------------------------------------------------
// Weight pre-convert: fp32 W -> bf16 MFMA frag layout (lane idx = col,
// k = quad*8+j). tiles 0..7 = Q heads (W_q pre-scaled by DH^-0.5 * log2e so
// attn softmax is exp2(s)), 8..15 = K, 16..23 = V.
// ---------------------------------------------------------------------------
__global__ __launch_bounds__(256) void wconv_kernel(
    const float* __restrict__ wmem, const float* __restrict__ wq,
    __bf16* __restrict__ Wb) {
  const int tile = blockIdx.x;
  const int tid = threadIdx.x;
  const int kc = tid >> 6, lane = tid & 63;
  const int quad = lane >> 4, col = lane & 15;
  const float* src;
  float scale = 1.0f;
  if (tile < 8) {
    src = wq + (tile * 16 + col) * D_;
    scale = 0.25f * LOG2E;  // DH^-0.5 and log2e folded into W_q
  } else if (tile < 16) {
    src = wmem + ((tile - 8) * 16 + col) * D_;
  } else {
    src = wmem + (128 + (tile - 16) * 16 + col) * D_;
  }
  const float* p = src + kc * 32 + quad * 8;
  bf16x8 w;
#pragma unroll
  for (int j = 0; j < 8; ++j) w[j] = (__bf16)(p[j] * scale);
  *(bf16x8*)(Wb + ((size_t)((tile * 4 + kc) * 64) + lane) * 8) = w;
}

// ---------------------------------------------------------------------------
// Projection (round-8, unchanged): 16 l-rows/block, 4 waves x 6 tiles.
// Qs natural; Ks tau-permuted (key bits 2<->3 swapped); V^T with mask folded:
// Vp[bh][tile][row][col]: rows 0-15 = V^T*mask, row 16 = mask (l-sum row),
// rows 17-31 unwritten (harmless garbage).
// ---------------------------------------------------------------------------
__global__ __launch_bounds__(256) void proj_kernel(
    const float* __restrict__ qin, const int* __restrict__ mask,
    const __bf16* __restrict__ Wb, __bf16* __restrict__ Qs,
    __bf16* __restrict__ Ks, __bf16* __restrict__ Vp) {
  __shared__ float xl[16][132];  // row stride >= 128 (D)!
  const int b = blockIdx.x >> 7;
  const int l0 = (blockIdx.x & 127) * 16;
  const int tid = threadIdx.x;

#pragma unroll
  for (int i = 0; i < 2; ++i) {
    int idx = i * 256 + tid;
    int d = idx >> 2;
    int l4 = (idx & 3) * 4;
    const float4 v = *(const float4*)&qin[(b * D_ + d) * L_ + l0 + l4];
    xl[l4 + 0][d] = v.x;
    xl[l4 + 1][d] = v.y;
    xl[l4 + 2][d] = v.z;
    xl[l4 + 3][d] = v.w;
  }

  // Mask row 16 of each head's Vp tile for our 16 columns.
  if (tid < 128) {
    const int hh = tid >> 4, c = tid & 15;
    const float mv = (float)mask[b * L_ + l0 + c];
    __bf16* dst = Vp +
        (((size_t)(b * H_ + hh) * 64 + (l0 >> 5)) * 32 + 16) * 32 +
        (l0 & 31) + c;
    *dst = (__bf16)mv;
  }
  __syncthreads();

  const int lane = tid & 63, wave = tid >> 6;
  const int quad = lane >> 4, col = lane & 15;

  bf16x8 af[4];
#pragma unroll
  for (int kc = 0; kc < 4; ++kc) {
    const float* s = &xl[col][kc * 32 + quad * 8];
#pragma unroll
    for (int j = 0; j < 8; ++j) af[kc][j] = (__bf16)s[j];
  }

  const int lbase = l0 + quad * 4;                       // Q rows
  const int quadK = ((quad & 1) << 1) | (quad >> 1);     // tau: swap bits 2,3
  const int lbaseK = l0 + quadK * 4;                     // K rows (permuted)
  const float mvv = (float)mask[b * L_ + l0 + col];      // V column mask

#pragma unroll
  for (int tt = 0; tt < 6; ++tt) {
    const int tile = wave * 6 + tt;
    floatx4 acc = {0.f, 0.f, 0.f, 0.f};
    const bool isV = (tile >= 16);
#pragma unroll
    for (int kc = 0; kc < 4; ++kc) {
      bf16x8 wf =
          *(const bf16x8*)(Wb + ((size_t)((tile * 4 + kc) * 64) + lane) * 8);
      acc = isV ? __builtin_amdgcn_mfma_f32_16x16x32_bf16(wf, af[kc], acc, 0, 0, 0)
                : __builtin_amdgcn_mfma_f32_16x16x32_bf16(af[kc], wf, acc, 0, 0, 0);
    }
    if (tile < 8) {  // Q head
      __bf16* dst = Qs + ((size_t)((b * H_ + tile) * L_) + lbase) * DH_ + col;
#pragma unroll
      for (int r = 0; r < 4; ++r) dst[r * DH_] = (__bf16)acc[r];
    } else if (tile < 16) {  // K head, tau-permuted rows
      __bf16* dst =
          Ks + ((size_t)((b * H_ + tile - 8) * L_) + lbaseK) * DH_ + col;
#pragma unroll
      for (int r = 0; r < 4; ++r) dst[r * DH_] = (__bf16)acc[r];
    } else {  // V^T * mask
      __bf16* dst = Vp +
          (((size_t)(b * H_ + (tile - 16)) * 64 + (l0 >> 5)) * 32 + quad * 4) * 32 +
          (l0 & 31) + col;
#pragma unroll
      for (int r = 0; r < 4; ++r) dst[r * 32] = (__bf16)(acc[r] * mvv);
    }
  }
}

// ---------------------------------------------------------------------------
// Attention v7: 32x32x16, transposed S, register P, zero mask logic —
// now with THREE independent chains per wave (tiles t, t+1, t+2 feed
// disjoint accumulators; 9 up-front 16B loads per body give MLP; chains
// are semantically independent, so no scheduler goodwill needed).
// grid = B*H*(L/128) = 1024 blocks x 4 waves; 48 chains/CU in flight.
// ---------------------------------------------------------------------------
__global__ __launch_bounds__(256, 4) void attn_kernel(
    const __bf16* __restrict__ Qs, const __bf16* __restrict__ Ks,
    const __bf16* __restrict__ Vp, float* __restrict__ out) {
  const int idx = blockIdx.x;
  const int qb = idx & 15;        // L/128
  const int h = (idx >> 4) & 7;
  const int b = idx >> 7;
  const int tid = threadIdx.x;
  const int lane = tid & 63, wave = tid >> 6;
  const int n = lane & 31, hh = lane >> 5;
  const int q0 = qb * 128 + wave * 32;
  const size_t bh = (size_t)(b * H_ + h);

  // Q B-frag: B[k=dh=8*hh+j][n=q]
  const bf16x8 qf = *(const bf16x8*)(Qs + (bh * L_ + q0 + n) * DH_ + 8 * hh);

  const __bf16* Kp = Ks + bh * L_ * DH_ + (size_t)n * DH_ + 8 * hh;
  const __bf16* Vq = Vp + (bh * 64 * 32 + (size_t)n) * 32 + 8 * hh;

  floatx16 acc0, acc1, acc2;
#pragma unroll
  for (int r = 0; r < 16; ++r) { acc0[r] = 0.f; acc1[r] = 0.f; acc2[r] = 0.f; }
  const floatx16 zz = acc0;

  // One chain: preloaded frags -> S -> exp2 -> PV.
  auto chain = [&](bf16x8 kf, bf16x8 v0, bf16x8 v1, floatx16& acc) {
    floatx16 s = __builtin_amdgcn_mfma_f32_32x32x16_bf16(kf, qf, zz, 0, 0, 0);
    bf16x8 pA, pB;
#pragma unroll
    for (int j = 0; j < 8; ++j) pA[j] = (__bf16)EXP2(s[j]);
#pragma unroll
    for (int j = 0; j < 8; ++j) pB[j] = (__bf16)EXP2(s[8 + j]);
    acc = __builtin_amdgcn_mfma_f32_32x32x16_bf16(v0, pA, acc, 0, 0, 0);
    acc = __builtin_amdgcn_mfma_f32_32x32x16_bf16(v1, pB, acc, 0, 0, 0);
  };

#pragma unroll 1
  for (int t = 0; t < 63; t += 3) {
    // 9 independent 16B loads up front (3 chains x {K, V lo, V hi})
    const __bf16* kp0 = Kp + (size_t)(t + 0) * 32 * DH_;
    const __bf16* kp1 = Kp + (size_t)(t + 1) * 32 * DH_;
    const __bf16* kp2 = Kp + (size_t)(t + 2) * 32 * DH_;
    const __bf16* vp0 = Vq + (size_t)(t + 0) * 1024;
    const __bf16* vp1 = Vq + (size_t)(t + 1) * 1024;
    const __bf16* vp2 = Vq + (size_t)(t + 2) * 1024;
    bf16x8 k0 = *(const bf16x8*)kp0;
    bf16x8 k1 = *(const bf16x8*)kp1;
    bf16x8 k2 = *(const bf16x8*)kp2;
    bf16x8 va0 = *(const bf16x8*)(vp0);
    bf16x8 va1 = *(const bf16x8*)(vp0 + 16);
    bf16x8 vb0 = *(const bf16x8*)(vp1);
    bf16x8 vb1 = *(const bf16x8*)(vp1 + 16);
    bf16x8 vc0 = *(const bf16x8*)(vp2);
    bf16x8 vc1 = *(const bf16x8*)(vp2 + 16);

    chain(k0, va0, va1, acc0);
    chain(k1, vb0, vb1, acc1);
    chain(k2, vc0, vc1, acc2);
  }
  {  // tile 63 (64 = 3*21 + 1)
    const __bf16* kp = Kp + (size_t)63 * 32 * DH_;
    const __bf16* vp = Vq + (size_t)63 * 1024;
    bf16x8 k0 = *(const bf16x8*)kp;
    bf16x8 v0 = *(const bf16x8*)(vp);
    bf16x8 v1 = *(const bf16x8*)(vp + 16);
    chain(k0, v0, v1, acc0);
  }

  floatx16 acc;
#pragma unroll
  for (int r = 0; r < 16; ++r) acc[r] = acc0[r] + acc1[r] + acc2[r];

  // l = row 16 of O^T = acc reg 8 on the hh==0 half; broadcast to hh==1.
  float lmine = acc[8];
  float lother = __shfl_xor(lmine, 32, 64);
  float inv = __builtin_amdgcn_rcpf(hh ? lother : lmine);

  // regs 0-7 are the 8 valid dh rows for this half: dh = (r&3)+8*(r>>2)+4*hh
  float* obase = out + ((size_t)(b * D_ + h * DH_)) * L_ + q0 + n;
#pragma unroll
  for (int r = 0; r < 8; ++r) {
    const int dh = (r & 3) + 8 * (r >> 2) + 4 * hh;
    obase[(size_t)dh * L_] = acc[r] * inv;
  }
}

// ---------------------------------------------------------------------------
extern "C" void kernel_launch(void* const* d_in, const int* in_sizes, int n_in,
                              void* d_out, int out_size, void* d_ws,
                              size_t ws_size, hipStream_t stream) {
  const float* queries = (const float*)d_in[0];  // [B, D, L] fp32
  const int*   mask    = (const int*)d_in[1];    // [B, L] int32
  const float* wmem    = (const float*)d_in[2];  // [2D, D] fp32
  const float* wq      = (const float*)d_in[3];  // [D, D] fp32
  float* out = (float*)d_out;                    // [B, D, L] fp32

  // Workspace: Qs 4 MiB | Ks 4 MiB | Vp 8 MiB.
  const size_t SEG = (size_t)B_ * H_ * L_ * DH_ * sizeof(__bf16);
  __bf16* Qs = (__bf16*)d_ws;
  __bf16* Ks = (__bf16*)((char*)d_ws + SEG);
  __bf16* Vp = (__bf16*)((char*)d_ws + 2 * SEG);

  // Wb (96 KiB) in d_out scratch: wconv writes, proj reads, attn then
  // overwrites ALL of d_out — stream-ordered, race-free.
  __bf16* Wb = (__bf16*)((char*)d_out + (4u << 20));

  wconv_kernel<<<24, 256, 0, stream>>>(wmem, wq, Wb);
  proj_kernel<<<B_ * (L_ / 16), 256, 0, stream>>>(queries, mask, Wb, Qs, Ks, Vp);
  attn_kernel<<<B_ * H_ * (L_ / 128), 256, 0, stream>>>(Qs, Ks, Vp, out);
}

// Round 10
// 117.928 us; speedup vs baseline: 1.1431x; 1.1431x over previous
//
#include <hip/hip_runtime.h>
#include <math.h>

// Problem constants
#define B_  8
#define D_  128
#define L_  2048
#define H_  8
#define DH_ 16

#define LOG2E 1.4426950408889634f

typedef __bf16 bf16x8 __attribute__((ext_vector_type(8)));
typedef float  floatx4 __attribute__((ext_vector_type(4)));
typedef float  floatx16 __attribute__((ext_vector_type(16)));

#if __has_builtin(__builtin_amdgcn_exp2f)
#define EXP2(x) __builtin_amdgcn_exp2f(x)
#else
#define EXP2(x) exp2f(x)
#endif

// ---------------------------------------------------------------------------
// Weight pre-convert: fp32 W -> bf16 MFMA frag layout (lane idx = col,
// k = quad*8+j). tiles 0..7 = Q heads (W_q pre-scaled by DH^-0.5 * log2e so
// attn softmax is exp2(s)), 8..15 = K, 16..23 = V.
// ---------------------------------------------------------------------------
__global__ __launch_bounds__(256) void wconv_kernel(
    const float* __restrict__ wmem, const float* __restrict__ wq,
    __bf16* __restrict__ Wb) {
  const int tile = blockIdx.x;
  const int tid = threadIdx.x;
  const int kc = tid >> 6, lane = tid & 63;
  const int quad = lane >> 4, col = lane & 15;
  const float* src;
  float scale = 1.0f;
  if (tile < 8) {
    src = wq + (tile * 16 + col) * D_;
    scale = 0.25f * LOG2E;  // DH^-0.5 and log2e folded into W_q
  } else if (tile < 16) {
    src = wmem + ((tile - 8) * 16 + col) * D_;
  } else {
    src = wmem + (128 + (tile - 16) * 16 + col) * D_;
  }
  const float* p = src + kc * 32 + quad * 8;
  bf16x8 w;
#pragma unroll
  for (int j = 0; j < 8; ++j) w[j] = (__bf16)(p[j] * scale);
  *(bf16x8*)(Wb + ((size_t)((tile * 4 + kc) * 64) + lane) * 8) = w;
}

// ---------------------------------------------------------------------------
// Projection (round-8, unchanged): 16 l-rows/block, 4 waves x 6 tiles.
// Qs natural; Ks tau-permuted (key bits 2<->3 swapped); V^T with mask folded:
// Vp[bh][tile][row][col]: rows 0-15 = V^T*mask, row 16 = mask (l-sum row),
// rows 17-31 unwritten (harmless garbage).
// ---------------------------------------------------------------------------
__global__ __launch_bounds__(256) void proj_kernel(
    const float* __restrict__ qin, const int* __restrict__ mask,
    const __bf16* __restrict__ Wb, __bf16* __restrict__ Qs,
    __bf16* __restrict__ Ks, __bf16* __restrict__ Vp) {
  __shared__ float xl[16][132];  // row stride >= 128 (D)!
  const int b = blockIdx.x >> 7;
  const int l0 = (blockIdx.x & 127) * 16;
  const int tid = threadIdx.x;

#pragma unroll
  for (int i = 0; i < 2; ++i) {
    int idx = i * 256 + tid;
    int d = idx >> 2;
    int l4 = (idx & 3) * 4;
    const float4 v = *(const float4*)&qin[(b * D_ + d) * L_ + l0 + l4];
    xl[l4 + 0][d] = v.x;
    xl[l4 + 1][d] = v.y;
    xl[l4 + 2][d] = v.z;
    xl[l4 + 3][d] = v.w;
  }

  // Mask row 16 of each head's Vp tile for our 16 columns.
  if (tid < 128) {
    const int hh = tid >> 4, c = tid & 15;
    const float mv = (float)mask[b * L_ + l0 + c];
    __bf16* dst = Vp +
        (((size_t)(b * H_ + hh) * 64 + (l0 >> 5)) * 32 + 16) * 32 +
        (l0 & 31) + c;
    *dst = (__bf16)mv;
  }
  __syncthreads();

  const int lane = tid & 63, wave = tid >> 6;
  const int quad = lane >> 4, col = lane & 15;

  bf16x8 af[4];
#pragma unroll
  for (int kc = 0; kc < 4; ++kc) {
    const float* s = &xl[col][kc * 32 + quad * 8];
#pragma unroll
    for (int j = 0; j < 8; ++j) af[kc][j] = (__bf16)s[j];
  }

  const int lbase = l0 + quad * 4;                       // Q rows
  const int quadK = ((quad & 1) << 1) | (quad >> 1);     // tau: swap bits 2,3
  const int lbaseK = l0 + quadK * 4;                     // K rows (permuted)
  const float mvv = (float)mask[b * L_ + l0 + col];      // V column mask

#pragma unroll
  for (int tt = 0; tt < 6; ++tt) {
    const int tile = wave * 6 + tt;
    floatx4 acc = {0.f, 0.f, 0.f, 0.f};
    const bool isV = (tile >= 16);
#pragma unroll
    for (int kc = 0; kc < 4; ++kc) {
      bf16x8 wf =
          *(const bf16x8*)(Wb + ((size_t)((tile * 4 + kc) * 64) + lane) * 8);
      acc = isV ? __builtin_amdgcn_mfma_f32_16x16x32_bf16(wf, af[kc], acc, 0, 0, 0)
                : __builtin_amdgcn_mfma_f32_16x16x32_bf16(af[kc], wf, acc, 0, 0, 0);
    }
    if (tile < 8) {  // Q head
      __bf16* dst = Qs + ((size_t)((b * H_ + tile) * L_) + lbase) * DH_ + col;
#pragma unroll
      for (int r = 0; r < 4; ++r) dst[r * DH_] = (__bf16)acc[r];
    } else if (tile < 16) {  // K head, tau-permuted rows
      __bf16* dst =
          Ks + ((size_t)((b * H_ + tile - 8) * L_) + lbaseK) * DH_ + col;
#pragma unroll
      for (int r = 0; r < 4; ++r) dst[r * DH_] = (__bf16)acc[r];
    } else {  // V^T * mask
      __bf16* dst = Vp +
          (((size_t)(b * H_ + (tile - 16)) * 64 + (l0 >> 5)) * 32 + quad * 4) * 32 +
          (l0 & 31) + col;
#pragma unroll
      for (int r = 0; r < 4; ++r) dst[r * 32] = (__bf16)(acc[r] * mvv);
    }
  }
}

// ---------------------------------------------------------------------------
// Attention v8 = round-8's proven 2-chain kernel + XCD-locality block remap.
//   blockIdx = qb*64 + bh  ->  idx%8 = bh%8: all 16 q-blocks sharing one
//   (b,h)'s K/V land on ONE XCD; per-XCD resident K/V = 8 bh x 192 KB =
//   1.5 MB < 4 MiB L2 -> K/V hits L2 (~200 cyc) instead of HBM (~900).
//   (Swizzle is a locality heuristic only — correctness unaffected.)
// grid = B*H*(L/128) = 1024 blocks x 4 waves (each wave: 32 q-rows).
// ---------------------------------------------------------------------------
__global__ __launch_bounds__(256, 4) void attn_kernel(
    const __bf16* __restrict__ Qs, const __bf16* __restrict__ Ks,
    const __bf16* __restrict__ Vp, float* __restrict__ out) {
  const int idx = blockIdx.x;
  const int qb = idx >> 6;        // q-major: 16 q-blocks
  const int bhi = idx & 63;       // bh minor -> idx%8 = h%8 fixed per bh
  const int h = bhi & 7;
  const int b = bhi >> 3;
  const int tid = threadIdx.x;
  const int lane = tid & 63, wave = tid >> 6;
  const int n = lane & 31, hh = lane >> 5;
  const int q0 = qb * 128 + wave * 32;
  const size_t bh = (size_t)(b * H_ + h);

  // Q B-frag: B[k=dh=8*hh+j][n=q]
  const bf16x8 qf = *(const bf16x8*)(Qs + (bh * L_ + q0 + n) * DH_ + 8 * hh);

  const __bf16* Kp = Ks + bh * L_ * DH_ + (size_t)n * DH_ + 8 * hh;
  const __bf16* Vq = Vp + (bh * 64 * 32 + (size_t)n) * 32 + 8 * hh;

  floatx16 acc0, acc1;
#pragma unroll
  for (int r = 0; r < 16; ++r) { acc0[r] = 0.f; acc1[r] = 0.f; }
  const floatx16 zz = acc0;

  auto tile = [&](int t, floatx16& acc) {
    // Kt A-frag: A[m=tau-row=n][k=dh]; V A-frag rows n (16B, unconditional)
    bf16x8 kf = *(const bf16x8*)(Kp + (size_t)t * 32 * DH_);
    const __bf16* vp = Vq + (size_t)t * 1024;
    bf16x8 v0 = *(const bf16x8*)(vp);
    bf16x8 v1 = *(const bf16x8*)(vp + 16);
    // S^T (32 keys x 32 q), C = 0
    floatx16 s = __builtin_amdgcn_mfma_f32_32x32x16_bf16(kf, qf, zz, 0, 0, 0);
    // P^T = exp2(S^T): packed pairs are exactly the PV B-frags
    bf16x8 pA, pB;
#pragma unroll
    for (int j = 0; j < 8; ++j) pA[j] = (__bf16)EXP2(s[j]);
#pragma unroll
    for (int j = 0; j < 8; ++j) pB[j] = (__bf16)EXP2(s[8 + j]);
    acc = __builtin_amdgcn_mfma_f32_32x32x16_bf16(v0, pA, acc, 0, 0, 0);
    acc = __builtin_amdgcn_mfma_f32_32x32x16_bf16(v1, pB, acc, 0, 0, 0);
  };

#pragma unroll 1
  for (int t = 0; t < 64; t += 2) {
    tile(t, acc0);
    tile(t + 1, acc1);
  }

  floatx16 acc;
#pragma unroll
  for (int r = 0; r < 16; ++r) acc[r] = acc0[r] + acc1[r];

  // l = row 16 of O^T = acc reg 8 on the hh==0 half; broadcast to hh==1.
  float lmine = acc[8];
  float lother = __shfl_xor(lmine, 32, 64);
  float inv = __builtin_amdgcn_rcpf(hh ? lother : lmine);

  // regs 0-7 are the 8 valid dh rows for this half: dh = (r&3)+8*(r>>2)+4*hh
  float* obase = out + ((size_t)(b * D_ + h * DH_)) * L_ + q0 + n;
#pragma unroll
  for (int r = 0; r < 8; ++r) {
    const int dh = (r & 3) + 8 * (r >> 2) + 4 * hh;
    obase[(size_t)dh * L_] = acc[r] * inv;
  }
}

// ---------------------------------------------------------------------------
extern "C" void kernel_launch(void* const* d_in, const int* in_sizes, int n_in,
                              void* d_out, int out_size, void* d_ws,
                              size_t ws_size, hipStream_t stream) {
  const float* queries = (const float*)d_in[0];  // [B, D, L] fp32
  const int*   mask    = (const int*)d_in[1];    // [B, L] int32
  const float* wmem    = (const float*)d_in[2];  // [2D, D] fp32
  const float* wq      = (const float*)d_in[3];  // [D, D] fp32
  float* out = (float*)d_out;                    // [B, D, L] fp32

  // Workspace: Qs 4 MiB | Ks 4 MiB | Vp 8 MiB.
  const size_t SEG = (size_t)B_ * H_ * L_ * DH_ * sizeof(__bf16);
  __bf16* Qs = (__bf16*)d_ws;
  __bf16* Ks = (__bf16*)((char*)d_ws + SEG);
  __bf16* Vp = (__bf16*)((char*)d_ws + 2 * SEG);

  // Wb (96 KiB) in d_out scratch: wconv writes, proj reads, attn then
  // overwrites ALL of d_out — stream-ordered, race-free.
  __bf16* Wb = (__bf16*)((char*)d_out + (4u << 20));

  wconv_kernel<<<24, 256, 0, stream>>>(wmem, wq, Wb);
  proj_kernel<<<B_ * (L_ / 16), 256, 0, stream>>>(queries, mask, Wb, Qs, Ks, Vp);
  attn_kernel<<<B_ * H_ * (L_ / 128), 256, 0, stream>>>(Qs, Ks, Vp, out);
}